// Round 14
// baseline (733.053 us; speedup 1.0000x reference)
//
#include <hip/hip_runtime.h>
#include <stdint.h>

// PointerNetwork forward, MI355X/gfx950 — 3 dispatches.
// R13 attribution: kA(chains)=174us. Validated model: GRU weights (197KB)
// stream from L2 EVERY step (96 floats/thread needed > ~88 allocator grant,
// across all configs) => 197KB/56B/cyc = 3520 cyc/step = ~92us. Fix is
// structural: lower half of w_hh cached in LDS ([384][68] pad, 2-way banks),
// upper half = 48 resident floats (safely under grant). P1 rewritten with
// register n-blocking (shfl /4, GI direct to global). kB/kC/kD merged.
// B=256, S=64, H=128.
// RNG: JAX threefry2x32 partitionable mode: bits = o0^o1 of tf(key,(0,j)).

#define BN 256
#define SN 64
#define HN 128
#define NEGV (-1.0e9f)
#define TINYF 1.17549435e-38f

__device__ __forceinline__ uint32_t rotl32(uint32_t v, int d) {
  return (v << d) | (v >> (32 - d));
}

__device__ __forceinline__ void threefry2x32(uint32_t k0, uint32_t k1,
                                             uint32_t x0, uint32_t x1,
                                             uint32_t& o0, uint32_t& o1) {
  uint32_t ks2 = k0 ^ k1 ^ 0x1BD11BDAu;
  x0 += k0; x1 += k1;
  x0 += x1; x1 = rotl32(x1, 13); x1 ^= x0;
  x0 += x1; x1 = rotl32(x1, 15); x1 ^= x0;
  x0 += x1; x1 = rotl32(x1, 26); x1 ^= x0;
  x0 += x1; x1 = rotl32(x1, 6);  x1 ^= x0;
  x0 += k1; x1 += ks2 + 1u;
  x0 += x1; x1 = rotl32(x1, 17); x1 ^= x0;
  x0 += x1; x1 = rotl32(x1, 29); x1 ^= x0;
  x0 += x1; x1 = rotl32(x1, 16); x1 ^= x0;
  x0 += x1; x1 = rotl32(x1, 24); x1 ^= x0;
  x0 += ks2; x1 += k0 + 2u;
  x0 += x1; x1 = rotl32(x1, 13); x1 ^= x0;
  x0 += x1; x1 = rotl32(x1, 15); x1 ^= x0;
  x0 += x1; x1 = rotl32(x1, 26); x1 ^= x0;
  x0 += x1; x1 = rotl32(x1, 6);  x1 ^= x0;
  x0 += k0; x1 += k1 + 3u;
  x0 += x1; x1 = rotl32(x1, 17); x1 ^= x0;
  x0 += x1; x1 = rotl32(x1, 29); x1 ^= x0;
  x0 += x1; x1 = rotl32(x1, 16); x1 ^= x0;
  x0 += x1; x1 = rotl32(x1, 24); x1 ^= x0;
  x0 += k1; x1 += ks2 + 4u;
  x0 += x1; x1 = rotl32(x1, 13); x1 ^= x0;
  x0 += x1; x1 = rotl32(x1, 15); x1 ^= x0;
  x0 += x1; x1 = rotl32(x1, 26); x1 ^= x0;
  x0 += x1; x1 = rotl32(x1, 6);  x1 ^= x0;
  x0 += ks2; x1 += k0 + 5u;
  o0 = x0; o1 = x1;
}

__device__ __forceinline__ float jax_gumbel(uint32_t k0, uint32_t k1, int j) {
  uint32_t o0, o1;
  threefry2x32(k0, k1, 0u, (uint32_t)j, o0, o1);
  uint32_t bits = o0 ^ o1;
  uint32_t ub = (bits >> 9) | 0x3F800000u;
  float u = __uint_as_float(ub) - 1.0f;
  u = fmaxf(u + TINYF, TINYF);
  return -logf(-logf(u));
}

__device__ __forceinline__ float ftanh(float x) {
  float ax = fabsf(x);
  float e = __expf(-2.0f * ax);
  float r = (1.0f - e) * __builtin_amdgcn_rcpf(1.0f + e);
  return copysignf(r, x);
}

__device__ __forceinline__ float fsig(float x) {
  return __builtin_amdgcn_rcpf(1.0f + __expf(-x));
}

// ---------------- K0: fold dyn path + step keys ----------------
__global__ void k0_dyn(const float* __restrict__ W_att, const float* __restrict__ dyn_w,
                       const float* __restrict__ dyn_b, float* __restrict__ Wd,
                       float* __restrict__ cv, uint32_t* __restrict__ keys) {
  int h = threadIdx.x;  // 128
  if (h < 64) {
    uint32_t o0, o1;
    threefry2x32(0u, 42u, 0u, (uint32_t)h, o0, o1);
    keys[2 * h] = o0; keys[2 * h + 1] = o1;
  }
  float w0 = 0.f, w1 = 0.f, cc = 0.f;
  for (int k = 0; k < HN; ++k) {
    float w = W_att[h * 384 + 128 + k];
    w0 = fmaf(w, dyn_w[2 * k + 0], w0);
    w1 = fmaf(w, dyn_w[2 * k + 1], w1);
    cc = fmaf(w, dyn_b[k], cc);
  }
  Wd[2 * h] = w0; Wd[2 * h + 1] = w1; cv[h] = cc;
}

// ---------------- kAB: x-chain + GI + GRU chain ----------------
// LDS floats: A(X) @0 (8192) | WL @8192 (26112: w_hh[384][68] lower-k half)
//             HC @34304 (256) | GSH @34560 (384)  => 139776 B
#define AB_A   0
#define AB_WL  8192
#define AB_HC  34304
#define AB_GSH 34560
#define AB_SMEM (34944 * 4)

__global__ __launch_bounds__(512) void kAB(
    const float* __restrict__ SE,
    const float* __restrict__ in_w, const float* __restrict__ in_b,
    const float* __restrict__ w_ih, const float* __restrict__ b_ih,
    const float* __restrict__ w_hh, const float* __restrict__ b_hh,
    float* __restrict__ GI_g, float* __restrict__ H_g) {
  extern __shared__ float sm[];
  float* A   = sm + AB_A;
  float* WL  = sm + AB_WL;
  float* HC  = sm + AB_HC;
  float* GSH = sm + AB_GSH;
  int b = blockIdx.x, t = threadIdx.x;

  if (t < 128) HC[t] = SE[b * 8192 + t * 64];  // x_{-1} = SE[b,:,0] (buf0)
  __syncthreads();

  // ---- P0: x-chain. 128 ml x 4 ks; 32 weight floats (resident) ----
  {
    int ml = t >> 2, ks = t & 3;
    float4 wv[8];
#pragma unroll
    for (int q = 0; q < 8; ++q)
      wv[q] = *(const float4*)(in_w + ml * HN + q * 16 + ks * 4);
    float bib = in_b[ml];
    for (int ii = 0; ii < SN; ++ii) {
      const float* xc = HC + (ii & 1) * 128;
      float* xn = HC + ((ii + 1) & 1) * 128;
      float a0 = 0.f, a1 = 0.f, a2 = 0.f, a3 = 0.f;
#pragma unroll
      for (int q = 0; q < 8; ++q) {
        float4 x4 = *(const float4*)(xc + q * 16 + ks * 4);
        a0 = fmaf(wv[q].x, x4.x, a0);
        a1 = fmaf(wv[q].y, x4.y, a1);
        a2 = fmaf(wv[q].z, x4.z, a2);
        a3 = fmaf(wv[q].w, x4.w, a3);
      }
      float s = (a0 + a1) + (a2 + a3);
      s += __shfl_xor(s, 1); s += __shfl_xor(s, 2);
      if (ks == 0) {
        float xv = s + bib;
        A[ii * 128 + ml] = xv;
        xn[ml] = xv;
      }
      __syncthreads();
    }
  }

  // ---- stage WL: lower-k half of w_hh into LDS [384][68] ----
  for (int idx = t; idx < 24576; idx += 512) {
    int m = idx >> 6, k = idx & 63;
    WL[m * 68 + k] = w_hh[m * 128 + k];
  }

  // ---- P1: GI = w_ih @ X + b_ih, register n-blocked, -> global ----
  // 128 ml x 4 ks; rows {ml+128j}; 8 n-groups of 8; 4 k-passes (24 wt floats)
  {
    int ml = t >> 2, ks = t & 3;
    float bi[3];
#pragma unroll
    for (int j = 0; j < 3; ++j) bi[j] = b_ih[ml + 128 * j];
    for (int g = 0; g < 8; ++g) {
      float acc[3][8];
#pragma unroll
      for (int j = 0; j < 3; ++j)
#pragma unroll
        for (int nn = 0; nn < 8; ++nn) acc[j][nn] = 0.f;
#pragma unroll
      for (int p = 0; p < 4; ++p) {
        float4 wv[3][2];
#pragma unroll
        for (int j = 0; j < 3; ++j) {
          wv[j][0] = *(const float4*)(w_ih + (ml + 128 * j) * HN + p * 32 + ks * 4);
          wv[j][1] = *(const float4*)(w_ih + (ml + 128 * j) * HN + p * 32 + 16 + ks * 4);
        }
#pragma unroll
        for (int nn = 0; nn < 8; ++nn) {
          int n = g * 8 + nn;
          float4 x0 = *(const float4*)(A + n * 128 + p * 32 + ks * 4);
          float4 x1 = *(const float4*)(A + n * 128 + p * 32 + 16 + ks * 4);
#pragma unroll
          for (int j = 0; j < 3; ++j) {
            float a = acc[j][nn];
            a = fmaf(wv[j][0].x, x0.x, a);
            a = fmaf(wv[j][0].y, x0.y, a);
            a = fmaf(wv[j][0].z, x0.z, a);
            a = fmaf(wv[j][0].w, x0.w, a);
            a = fmaf(wv[j][1].x, x1.x, a);
            a = fmaf(wv[j][1].y, x1.y, a);
            a = fmaf(wv[j][1].z, x1.z, a);
            a = fmaf(wv[j][1].w, x1.w, a);
            acc[j][nn] = a;
          }
        }
      }
#pragma unroll
      for (int j = 0; j < 3; ++j)
#pragma unroll
        for (int nn = 0; nn < 8; ++nn) {
          float s = acc[j][nn];
          s += __shfl_xor(s, 1); s += __shfl_xor(s, 2);
          if (ks == 0)
            GI_g[b * 24576 + (g * 8 + nn) * 384 + ml + 128 * j] = s + bi[j];
        }
    }
  }
  __threadfence();   // GI_g writes visible before same-block reads in P2
  if (t < 256) HC[t] = 0.f;
  __syncthreads();

  // ---- P2: GRU chain. lower-k weights from WL (LDS), upper-k resident ----
  {
    int ml = t >> 2, ks = t & 3;
    const float4* WL4 = (const float4*)WL;   // quad idx = m*17 + q*4 + ks
    float4 wu[3][4]; float bh[3];
#pragma unroll
    for (int j = 0; j < 3; ++j) {
#pragma unroll
      for (int q = 0; q < 4; ++q)
        wu[j][q] = *(const float4*)(w_hh + (ml + 128 * j) * HN + 64 + q * 16 + ks * 4);
      bh[j] = b_hh[ml + 128 * j];
    }
    // depth-2 GI prefetch (t<384 lanes hold one gi value each)
    float gv0 = 0.f, gv1 = 0.f;
    if (t < 384) {
      gv0 = GI_g[b * 24576 + 0 * 384 + t];
      gv1 = GI_g[b * 24576 + 1 * 384 + t];
    }
    float hp = 0.f;
    for (int ii = 0; ii < SN; ++ii) {
      const float* hcr = HC + (ii & 1) * 128;
      float* hcw = HC + ((ii + 1) & 1) * 128;
      float s0 = 0.f, s1 = 0.f, s2 = 0.f;
#pragma unroll
      for (int q = 0; q < 4; ++q) {
        float4 xl = *(const float4*)(hcr + q * 16 + ks * 4);
        float4 xu = *(const float4*)(hcr + 64 + q * 16 + ks * 4);
        float4 w0 = WL4[(ml) * 17 + q * 4 + ks];
        float4 w1 = WL4[(ml + 128) * 17 + q * 4 + ks];
        float4 w2 = WL4[(ml + 256) * 17 + q * 4 + ks];
        s0 = fmaf(w0.x, xl.x, s0); s0 = fmaf(w0.y, xl.y, s0);
        s0 = fmaf(w0.z, xl.z, s0); s0 = fmaf(w0.w, xl.w, s0);
        s1 = fmaf(w1.x, xl.x, s1); s1 = fmaf(w1.y, xl.y, s1);
        s1 = fmaf(w1.z, xl.z, s1); s1 = fmaf(w1.w, xl.w, s1);
        s2 = fmaf(w2.x, xl.x, s2); s2 = fmaf(w2.y, xl.y, s2);
        s2 = fmaf(w2.z, xl.z, s2); s2 = fmaf(w2.w, xl.w, s2);
        s0 = fmaf(wu[0][q].x, xu.x, s0); s0 = fmaf(wu[0][q].y, xu.y, s0);
        s0 = fmaf(wu[0][q].z, xu.z, s0); s0 = fmaf(wu[0][q].w, xu.w, s0);
        s1 = fmaf(wu[1][q].x, xu.x, s1); s1 = fmaf(wu[1][q].y, xu.y, s1);
        s1 = fmaf(wu[1][q].z, xu.z, s1); s1 = fmaf(wu[1][q].w, xu.w, s1);
        s2 = fmaf(wu[2][q].x, xu.x, s2); s2 = fmaf(wu[2][q].y, xu.y, s2);
        s2 = fmaf(wu[2][q].z, xu.z, s2); s2 = fmaf(wu[2][q].w, xu.w, s2);
      }
      s0 += __shfl_xor(s0, 1); s0 += __shfl_xor(s0, 2);
      s1 += __shfl_xor(s1, 1); s1 += __shfl_xor(s1, 2);
      s2 += __shfl_xor(s2, 1); s2 += __shfl_xor(s2, 2);
      if (t < 384) GSH[t] = gv0;
      gv0 = gv1;
      gv1 = (ii + 2 < SN && t < 384) ? GI_g[b * 24576 + (ii + 2) * 384 + t] : 0.f;
      __syncthreads();   // GSH ready; all hcr reads complete
      if (ks == 0) {
        float r = fsig(GSH[ml] + s0 + bh[0]);
        float z = fsig(GSH[128 + ml] + s1 + bh[1]);
        float nn = ftanh(GSH[256 + ml] + r * (s2 + bh[2]));
        float hn = (1.0f - z) * nn + z * hp;
        hcw[ml] = hn;
        H_g[(b * SN + ii) * HN + ml] = hn;
        hp = hn;
      }
      __syncthreads();
    }
  }
}

// ---------------- kBCD: WhC + Ust + scores + gumbels + sampling ----------
// LDS floats: Hl @0 (8192) | SET @8192 (8448) | WHC @16640 (8192)
//             UT @24832 (8448)  => 133120 B.  P/G overwrite Hl after P5.
#define BC_H   0
#define BC_SET 8192
#define BC_WHC 16640
#define BC_UT  24832
#define BC_SMEM (33280 * 4)

__global__ __launch_bounds__(512) void kBCD(
    const float* __restrict__ SE, const float* __restrict__ dynamic,
    const float* __restrict__ W_att, const float* __restrict__ v_att,
    const float* __restrict__ Wd, const float* __restrict__ cv,
    const uint32_t* __restrict__ keys,
    const float* __restrict__ H_g, float* __restrict__ out) {
  extern __shared__ float sm[];
  float* Hl  = sm + BC_H;
  float* SET = sm + BC_SET;
  float* WHC = sm + BC_WHC;
  float* UT  = sm + BC_UT;
  int b = blockIdx.x, t = threadIdx.x;
#pragma unroll
  for (int p = 0; p < 4; ++p)
    ((float4*)Hl)[p * 512 + t] = ((const float4*)(H_g + b * 8192))[p * 512 + t];
  // P4: stage SE[b] transposed (disjoint from Hl; no barrier needed yet)
  for (int p = 0; p < 16; ++p) {
    int idx = p * 512 + t;
    int h = idx >> 6, s = idx & 63;
    SET[s * 132 + h] = SE[b * 8192 + idx];
  }
  __syncthreads();

  // ---- P3: WhC = W_att3 @ H. 128 ml x 4 ks; 1 row; 32 wt floats ----
  {
    int ml = t >> 2, ks = t & 3;
    float4 wv[8];
#pragma unroll
    for (int q = 0; q < 8; ++q)
      wv[q] = *(const float4*)(W_att + ml * 384 + 256 + q * 16 + ks * 4);
    for (int n = 0; n < SN; ++n) {
      float a0 = 0.f, a1 = 0.f, a2 = 0.f, a3 = 0.f;
#pragma unroll
      for (int q = 0; q < 8; ++q) {
        float4 x4 = *(const float4*)(Hl + n * 128 + q * 16 + ks * 4);
        a0 = fmaf(wv[q].x, x4.x, a0);
        a1 = fmaf(wv[q].y, x4.y, a1);
        a2 = fmaf(wv[q].z, x4.z, a2);
        a3 = fmaf(wv[q].w, x4.w, a3);
      }
      float s = (a0 + a1) + (a2 + a3);
      s += __shfl_xor(s, 1); s += __shfl_xor(s, 2);
      if (ks == 0) WHC[n * 128 + ml] = s;
    }
  }

  // ---- P5: UT[m][66] = (W_att1 @ SE^T)[s][m] + dyn fold ----
  {
    int ml = t >> 2, ks = t & 3;
    float4 wv[8];
#pragma unroll
    for (int q = 0; q < 8; ++q)
      wv[q] = *(const float4*)(W_att + ml * 384 + q * 16 + ks * 4);
    float wd0 = Wd[2 * ml], wd1 = Wd[2 * ml + 1], cvm = cv[ml];
    for (int n = 0; n < SN; ++n) {
      float a0 = 0.f, a1 = 0.f, a2 = 0.f, a3 = 0.f;
#pragma unroll
      for (int q = 0; q < 8; ++q) {
        float4 x4 = *(const float4*)(SET + n * 132 + q * 16 + ks * 4);
        a0 = fmaf(wv[q].x, x4.x, a0);
        a1 = fmaf(wv[q].y, x4.y, a1);
        a2 = fmaf(wv[q].z, x4.z, a2);
        a3 = fmaf(wv[q].w, x4.w, a3);
      }
      float s = (a0 + a1) + (a2 + a3);
      s += __shfl_xor(s, 1); s += __shfl_xor(s, 2);
      if (ks == 0) {
        float d0 = dynamic[b * 128 + n], d1 = dynamic[b * 128 + 64 + n];
        UT[ml * 66 + n] = s + wd0 * d0 + wd1 * d1 + cvm;
      }
    }
    __syncthreads();
  }

  // ---- P6: scores -> sm[0:4096). wave w owns i = w*8+j ----
  {
    int s = t & 63, w = t >> 6;
    float acc[8];
#pragma unroll
    for (int j = 0; j < 8; ++j) acc[j] = 0.f;
    for (int h = 0; h < HN; h += 4) {
      float u0 = UT[(h + 0) * 66 + s];
      float u1 = UT[(h + 1) * 66 + s];
      float u2 = UT[(h + 2) * 66 + s];
      float u3 = UT[(h + 3) * 66 + s];
      float4 v4 = *(const float4*)(v_att + h);
#pragma unroll
      for (int j = 0; j < 8; ++j) {
        float4 wh = *(const float4*)(WHC + (w * 8 + j) * 128 + h);
        float a = acc[j];
        a = fmaf(v4.x, ftanh(u0 + wh.x), a);
        a = fmaf(v4.y, ftanh(u1 + wh.y), a);
        a = fmaf(v4.z, ftanh(u2 + wh.z), a);
        a = fmaf(v4.w, ftanh(u3 + wh.w), a);
        acc[j] = a;
      }
    }
    __syncthreads();  // all UT/WHC/Hl reads done; sm[0:8192) rewritable
#pragma unroll
    for (int j = 0; j < 8; ++j) sm[(w * 8 + j) * 64 + s] = acc[j];
  }

  // ---- P7: gumbels -> sm[4096:8192) ----
  {
    float* G = sm + 4096;
    for (int p = 0; p < 8; ++p) {
      int idx = p * 512 + t;
      int i = idx >> 6;
      G[idx] = jax_gumbel(keys[2 * i], keys[2 * i + 1], b * 64 + (idx & 63));
    }
    __syncthreads();
  }

  // ---- P8: serial sampling (wave 0) ----
  if (t < 64) {
    const float* Pl = sm;
    const float* Gl = sm + 4096;
    int s = t;
    bool visited = false;
    for (int i = 0; i < SN; ++i) {
      float score = Pl[i * 64 + s];
      bool allowed = (i == 0) ? (s == 0) : (!visited);
      float logit = allowed ? score : NEGV;
      float z = logit + Gl[i * 64 + s];
      float bz = z; int bi = s;
#pragma unroll
      for (int off = 32; off > 0; off >>= 1) {
        float oz = __shfl_xor(bz, off);
        int oi = __shfl_xor(bi, off);
        if (oz > bz || (oz == bz && oi < bi)) { bz = oz; bi = oi; }
      }
      int ptr = bi;
      float m = logit;
#pragma unroll
      for (int off = 32; off > 0; off >>= 1) m = fmaxf(m, __shfl_xor(m, off));
      float e = expf(logit - m);
      float sum = e;
#pragma unroll
      for (int off = 32; off > 0; off >>= 1) sum += __shfl_xor(sum, off);
      float chosen = __shfl(logit, ptr);
      float logp = (chosen - m) - logf(sum);
      if (s == ptr) visited = true;
      if (s == 0) {
        out[b * SN + i] = (float)ptr;
        out[BN * SN + b * SN + i] = logp;
      }
    }
  }
}

// ---------------- launch ----------------
extern "C" void kernel_launch(void* const* d_in, const int* in_sizes, int n_in,
                              void* d_out, int out_size, void* d_ws, size_t ws_size,
                              hipStream_t stream) {
  const float* SE    = (const float*)d_in[1];
  const float* dynam = (const float*)d_in[2];
  const float* dyn_w = (const float*)d_in[3];
  const float* dyn_b = (const float*)d_in[4];
  const float* in_w  = (const float*)d_in[5];
  const float* in_b  = (const float*)d_in[6];
  const float* w_ih  = (const float*)d_in[7];
  const float* w_hh  = (const float*)d_in[8];
  const float* b_ih  = (const float*)d_in[9];
  const float* b_hh  = (const float*)d_in[10];
  const float* W_att = (const float*)d_in[11];
  const float* v_att = (const float*)d_in[12];
  float* out = (float*)d_out;
  float* ws = (float*)d_ws;

  // workspace (floats): GI_g @0 (6.29M) | H_g @6291456 (2.10M) | Wd/cv/keys
  float* GI_g = ws;
  float* H_g  = ws + 6291456;
  float* Wd   = ws + 8388608;
  float* cv   = Wd + 256;
  uint32_t* keys = (uint32_t*)(cv + 128);

  (void)hipFuncSetAttribute((const void*)kAB,
                            hipFuncAttributeMaxDynamicSharedMemorySize, AB_SMEM);
  (void)hipFuncSetAttribute((const void*)kBCD,
                            hipFuncAttributeMaxDynamicSharedMemorySize, BC_SMEM);

  hipLaunchKernelGGL(k0_dyn, dim3(1), dim3(128), 0, stream,
                     W_att, dyn_w, dyn_b, Wd, cv, keys);
  hipLaunchKernelGGL(kAB, dim3(BN), dim3(512), AB_SMEM, stream,
                     SE, in_w, in_b, w_ih, b_ih, w_hh, b_hh, GI_g, H_g);
  hipLaunchKernelGGL(kBCD, dim3(BN), dim3(512), BC_SMEM, stream,
                     SE, dynam, W_att, v_att, Wd, cv, keys, H_g, out);
}